// Round 3
// baseline (725.365 us; speedup 1.0000x reference)
//
#include <hip/hip_runtime.h>
#include <math.h>

// GCN 2-layer + pool + head, destination-bucketed LDS-accumulator formulation.
//
// Buckets: node v belongs to bucket b = v / NPB. Edges are partitioned into
// per-bucket segments (fixed capacity CAP), each edge packed into one int:
//   packed = row | (c_local << 17)     (row < 2^17; c_local < NPB)
// Each layer: one workgroup per bucket accumulates messages into an LDS
// array [NPB][16] with LDS atomics — no global float atomics, contiguous
// output writes.
//
// Workspace (4B units): cursor[512] | dinv[N] | packed[NB*CAP] | h0[16N]
//                       | h1[16N] | g[16G]   (~27.6 MB for N=100k)

#define NPB     200     // nodes per bucket
#define NBMAX   512
#define CAP     7168    // bucket capacity: mean E/NB=6400, sigma~80 -> 9.6 sigma
#define PT_TILE 8192    // edges per partition workgroup

__global__ void k_init(int* cursor, float* g, int NB, int G16) {
    int i = blockIdx.x * blockDim.x + threadIdx.x;
    if (i < NB) cursor[i] = i * CAP;
    if (i < G16) g[i] = 0.0f;
}

// Partition edges into buckets. Per tile: LDS histogram -> one global-cursor
// reservation per (tile,bucket) -> contiguous run writes (~64B each).
__global__ void k_partition(const int* __restrict__ row, const int* __restrict__ col,
                            int* cursor, int* __restrict__ packed, int E) {
    __shared__ int hist[NBMAX];
    __shared__ int rstart[NBMAX];
    __shared__ int loff[NBMAX];
    int tid = threadIdx.x;
    for (int b = tid; b < NBMAX; b += blockDim.x) hist[b] = 0;
    __syncthreads();
    int e0 = blockIdx.x * PT_TILE;
#pragma unroll
    for (int j = 0; j < PT_TILE / 256; ++j) {
        int e = e0 + tid + j * 256;
        if (e < E) atomicAdd(&hist[col[e] / NPB], 1);
    }
    __syncthreads();
    for (int b = tid; b < NBMAX; b += blockDim.x) {
        loff[b] = 0;
        if (hist[b] > 0) rstart[b] = atomicAdd(&cursor[b], hist[b]);
    }
    __syncthreads();
#pragma unroll
    for (int j = 0; j < PT_TILE / 256; ++j) {
        int e = e0 + tid + j * 256;
        if (e < E) {
            int c = col[e];
            int b = c / NPB;
            int rank = atomicAdd(&loff[b], 1);
            packed[rstart[b] + rank] = row[e] | ((c - b * NPB) << 17);
        }
    }
}

// Per-bucket degree via LDS histogram; dinv = rsqrt(deg+1) written coalesced.
__global__ void k_degree(const int* __restrict__ packed, const int* __restrict__ cursor,
                         float* __restrict__ dinv, int N) {
    __shared__ int deg[NPB];
    int b = blockIdx.x, tid = threadIdx.x;
    for (int i = tid; i < NPB; i += blockDim.x) deg[i] = 0;
    __syncthreads();
    int s = b * CAP, e_end = cursor[b];
    for (int e = s + tid; e < e_end; e += blockDim.x)
        atomicAdd(&deg[packed[e] >> 17], 1);
    __syncthreads();
    int v0 = b * NPB;
    for (int i = tid; i < NPB; i += blockDim.x)
        if (v0 + i < N) dinv[v0 + i] = rsqrtf((float)(1 + deg[i]));
}

// h0[v][k] = sum_c x[v][c] * W1[c][k]   (W1 is 3x16 row-major)
__global__ void k_xw1(const float* __restrict__ x, const float* __restrict__ W1,
                      float* __restrict__ h0, int N) {
    int t = blockIdx.x * blockDim.x + threadIdx.x;
    if (t >= N * 16) return;
    int v = t >> 4, k = t & 15;
    float x0 = x[v * 3 + 0], x1 = x[v * 3 + 1], x2 = x[v * 3 + 2];
    h0[t] = x0 * W1[k] + x1 * W1[16 + k] + x2 * W1[32 + k];
}

// One workgroup per bucket; LDS accumulator [NPB][16].
// Lane layout: k = tid&15 (feature), slot = tid>>4; 4 edges batched per slot
// per iteration for memory-level parallelism.
// MODE 0: dst[v][k] = relu(dv*acc + dv^2*src[v][k] + bias[k])
// MODE 1: g[batch[v]][k] += val  (LDS-reduced per local graph, then few atomics)
template<int MODE>
__global__ __launch_bounds__(512)
void k_gather(const int* __restrict__ packed, const int* __restrict__ cursor,
              const float* __restrict__ dinv, const float* __restrict__ src,
              const float* __restrict__ bias, const int* __restrict__ batch,
              float* __restrict__ dst, int N) {
    __shared__ float acc[NPB * 16];
    __shared__ float pacc[NPB * 16];
    int b = blockIdx.x, tid = threadIdx.x;
    for (int i = tid; i < NPB * 16; i += blockDim.x) {
        acc[i] = 0.0f;
        if (MODE == 1) pacc[i] = 0.0f;
    }
    __syncthreads();
    int s = b * CAP;
    int n = cursor[b] - s;
    int v0 = b * NPB;
    int k = tid & 15, slot = tid >> 4;   // 32 slots/block
    for (int e = slot * 4; e < n; e += 128) {
        int pk[4]; int cl[4]; float w[4]; float val4[4]; bool ok[4];
#pragma unroll
        for (int j = 0; j < 4; ++j) {
            ok[j] = (e + j) < n;
            pk[j] = ok[j] ? packed[s + e + j] : 0;
        }
#pragma unroll
        for (int j = 0; j < 4; ++j) {
            int r = pk[j] & 0x1FFFF;
            cl[j] = pk[j] >> 17;
            w[j]  = ok[j] ? dinv[r] : 0.0f;
            val4[j] = ok[j] ? src[r * 16 + k] : 0.0f;
        }
#pragma unroll
        for (int j = 0; j < 4; ++j)
            if (ok[j]) atomicAdd(&acc[cl[j] * 16 + k], w[j] * val4[j]);
    }
    __syncthreads();
    int vcnt = min(NPB, N - v0);
    if (MODE == 0) {
        for (int i = tid; i < vcnt * 16; i += blockDim.x) {
            int vl = i >> 4, kk = i & 15;
            int v = v0 + vl;
            float dv = dinv[v];
            float val = dv * acc[i] + dv * dv * src[v * 16 + kk] + bias[kk];
            dst[v * 16 + kk] = fmaxf(val, 0.0f);
        }
    } else {
        int b0 = batch[v0];
        for (int i = tid; i < vcnt * 16; i += blockDim.x) {
            int vl = i >> 4, kk = i & 15;
            int v = v0 + vl;
            float dv = dinv[v];
            float val = dv * acc[i] + dv * dv * src[v * 16 + kk] + bias[kk];
            atomicAdd(&pacc[(batch[v] - b0) * 16 + kk], val);  // batch sorted: diff < NPB
        }
        __syncthreads();
        int grange = batch[v0 + vcnt - 1] - b0 + 1;
        for (int i = tid; i < grange * 16; i += blockDim.x)
            atomicAdd(&dst[(b0 + (i >> 4)) * 16 + (i & 15)], pacc[i]);
    }
}

// t2[v][k] = sum_j h1[v][j] * W2[j][k]   (W2 16x16 row-major, staged in LDS)
__global__ void k_hw2(const float* __restrict__ h1, const float* __restrict__ W2,
                      float* __restrict__ t2, int N) {
    __shared__ float sW[256];
    if (threadIdx.x < 256) sW[threadIdx.x] = W2[threadIdx.x];
    __syncthreads();
    int t = blockIdx.x * blockDim.x + threadIdx.x;
    if (t >= N * 16) return;
    int v = t >> 4, k = t & 15;
    const float* hr = h1 + v * 16;
    float acc = 0.0f;
#pragma unroll
    for (int j = 0; j < 16; ++j) acc += hr[j] * sW[j * 16 + k];
    t2[t] = acc;
}

// logits = g @ Wl + bl (16x7), then log_softmax over 7. One thread per graph.
__global__ void k_head(const float* __restrict__ g, const float* __restrict__ Wl,
                       const float* __restrict__ bl, float* __restrict__ out, int G) {
    int gi = blockIdx.x * blockDim.x + threadIdx.x;
    if (gi >= G) return;
    float gv[16];
#pragma unroll
    for (int kk = 0; kk < 16; ++kk) gv[kk] = g[gi * 16 + kk];
    float lo[7];
    float mx = -1e30f;
#pragma unroll
    for (int j = 0; j < 7; ++j) {
        float a = bl[j];
#pragma unroll
        for (int kk = 0; kk < 16; ++kk) a += gv[kk] * Wl[kk * 7 + j];
        lo[j] = a;
        mx = fmaxf(mx, a);
    }
    float ssum = 0.0f;
#pragma unroll
    for (int j = 0; j < 7; ++j) ssum += expf(lo[j] - mx);
    float lse = mx + logf(ssum);
#pragma unroll
    for (int j = 0; j < 7; ++j) out[gi * 7 + j] = lo[j] - lse;
}

extern "C" void kernel_launch(void* const* d_in, const int* in_sizes, int n_in,
                              void* d_out, int out_size, void* d_ws, size_t ws_size,
                              hipStream_t stream) {
    const float* x     = (const float*)d_in[0];
    const int*   ei    = (const int*)d_in[1];   // row = ei[0:E), col = ei[E:2E)
    const int*   batch = (const int*)d_in[3];
    const float* W1 = (const float*)d_in[4];
    const float* b1 = (const float*)d_in[5];
    const float* W2 = (const float*)d_in[6];
    const float* b2 = (const float*)d_in[7];
    const float* Wl = (const float*)d_in[8];
    const float* bl = (const float*)d_in[9];
    float* out = (float*)d_out;

    const int N = in_sizes[0] / 3;   // 100000 (< 2^17, required by packing)
    const int E = in_sizes[1] / 2;
    const int G = out_size / 7;
    const int NB = (N + NPB - 1) / NPB;   // 500

    const int* row = ei;
    const int* col = ei + E;

    int*   cursor = (int*)d_ws;               // NBMAX
    float* dinv   = (float*)(cursor + NBMAX); // N
    int*   packed = (int*)(dinv + N);         // NB*CAP
    float* h0     = (float*)(packed + NB * CAP); // 16N
    float* h1     = h0 + 16 * N;              // 16N
    float* g      = h1 + 16 * N;              // 16G
    float* t2     = h0;                       // alias: h0 dead after gather1

    const int n16 = N * 16;
    const int TB = 256;

    k_init<<<(max(NB, G * 16) + TB - 1) / TB, TB, 0, stream>>>(cursor, g, NB, G * 16);
    k_partition<<<(E + PT_TILE - 1) / PT_TILE, TB, 0, stream>>>(row, col, cursor, packed, E);
    k_degree<<<NB, TB, 0, stream>>>(packed, cursor, dinv, N);
    k_xw1<<<(n16 + TB - 1) / TB, TB, 0, stream>>>(x, W1, h0, N);
    k_gather<0><<<NB, 512, 0, stream>>>(packed, cursor, dinv, h0, b1, batch, h1, N);
    k_hw2<<<(n16 + TB - 1) / TB, TB, 0, stream>>>(h1, W2, t2, N);
    k_gather<1><<<NB, 512, 0, stream>>>(packed, cursor, dinv, t2, b2, batch, g, N);
    k_head<<<(G + TB - 1) / TB, TB, 0, stream>>>(g, Wl, bl, out, G);
}

// Round 4
// 693.851 us; speedup vs baseline: 1.0454x; 1.0454x over previous
//
#include <hip/hip_runtime.h>
#include <math.h>

// GCN 2-layer + pool + head. Destination-bucketed, one-thread-per-edge,
// LDS accumulators, dinv folded into features.
//
// Bucket b = v / NPB (NPB=100, NB=1000). Edges partitioned into per-bucket
// segments of capacity CAP, packed = row | (c_local<<17).
//   layer features are pre-scaled: h0s[v] = dinv[v]*(x[v]@W1)
//   gather acc[c] = sum_{(r->c)} h0s[r]; out = dinv[c]*(acc + h0s[c]) + bias
//
// Workspace: cursor[1024] | dinv[N] | packed[NB*CAP] | h0s[16N] | t2s[16N]
//            | g[16G]  ~= 28.6 MB.

#define NPB     100
#define NBMAX   1024
#define CAP     3840    // mean E/NB = 3200, sigma ~57 -> 11 sigma margin
#define PT_TILE 8192

__global__ void k_init(int* cursor, float* g, int NB, int G16) {
    int i = blockIdx.x * blockDim.x + threadIdx.x;
    if (i < NB) cursor[i] = i * CAP;
    if (i < G16) g[i] = 0.0f;
}

__global__ __launch_bounds__(512)
void k_partition(const int* __restrict__ row, const int* __restrict__ col,
                 int* cursor, int* __restrict__ packed, int E) {
    __shared__ int hist[NBMAX];
    __shared__ int rstart[NBMAX];
    __shared__ int loff[NBMAX];
    int tid = threadIdx.x;
    for (int b = tid; b < NBMAX; b += 512) hist[b] = 0;
    __syncthreads();
    int e0 = blockIdx.x * PT_TILE;
#pragma unroll
    for (int j = 0; j < PT_TILE / 512; ++j) {
        int e = e0 + tid + j * 512;
        if (e < E) atomicAdd(&hist[col[e] / NPB], 1);
    }
    __syncthreads();
    for (int b = tid; b < NBMAX; b += 512) {
        loff[b] = 0;
        if (hist[b] > 0) rstart[b] = atomicAdd(&cursor[b], hist[b]);
    }
    __syncthreads();
#pragma unroll
    for (int j = 0; j < PT_TILE / 512; ++j) {
        int e = e0 + tid + j * 512;
        if (e < E) {
            int c = col[e];
            int b = c / NPB;
            int rank = atomicAdd(&loff[b], 1);
            packed[rstart[b] + rank] = row[e] | ((c - b * NPB) << 17);
        }
    }
}

// Per-bucket degree (LDS hist) -> dinv, then h0s = dinv * (x @ W1), fused.
__global__ __launch_bounds__(512)
void k_deg_xw1(const int* __restrict__ packed, const int* __restrict__ cursor,
               const float* __restrict__ x, const float* __restrict__ W1,
               float* __restrict__ dinv, float* __restrict__ h0s, int N) {
    __shared__ int   deg[NPB];
    __shared__ float sdinv[NPB];
    __shared__ float sW1[48];
    int b = blockIdx.x, tid = threadIdx.x;
    if (tid < NPB) deg[tid] = 0;
    if (tid < 48) sW1[tid] = W1[tid];
    __syncthreads();
    int s = b * CAP, n = cursor[b] - s;
    for (int i = tid; i < n; i += 512)
        atomicAdd(&deg[packed[s + i] >> 17], 1);
    __syncthreads();
    int v0 = b * NPB;
    int vcnt = min(NPB, N - v0);
    if (tid < vcnt) {
        float dv = rsqrtf((float)(1 + deg[tid]));   // +1 self-loop
        sdinv[tid] = dv;
        dinv[v0 + tid] = dv;
    }
    __syncthreads();
    for (int i = tid; i < vcnt * 16; i += 512) {
        int vl = i >> 4, k = i & 15, v = v0 + vl;
        float x0 = x[v * 3 + 0], x1 = x[v * 3 + 1], x2 = x[v * 3 + 2];
        h0s[v * 16 + k] = sdinv[vl] * (x0 * sW1[k] + x1 * sW1[16 + k] + x2 * sW1[32 + k]);
    }
}

#define EDGE_ACC_LOOP(SRC)                                                   \
    for (int i = tid; i < n; i += 512) {                                     \
        int pk = packed[s + i];                                              \
        int r = pk & 0x1FFFF, cl = pk >> 17;                                 \
        const float4* rp = (const float4*)(SRC) + r * 4;                     \
        float4 a0 = rp[0], a1 = rp[1], a2 = rp[2], a3 = rp[3];               \
        float* ar = acc + cl * 17;                                           \
        atomicAdd(ar + 0,  a0.x); atomicAdd(ar + 1,  a0.y);                  \
        atomicAdd(ar + 2,  a0.z); atomicAdd(ar + 3,  a0.w);                  \
        atomicAdd(ar + 4,  a1.x); atomicAdd(ar + 5,  a1.y);                  \
        atomicAdd(ar + 6,  a1.z); atomicAdd(ar + 7,  a1.w);                  \
        atomicAdd(ar + 8,  a2.x); atomicAdd(ar + 9,  a2.y);                  \
        atomicAdd(ar + 10, a2.z); atomicAdd(ar + 11, a2.w);                  \
        atomicAdd(ar + 12, a3.x); atomicAdd(ar + 13, a3.y);                  \
        atomicAdd(ar + 14, a3.z); atomicAdd(ar + 15, a3.w);                  \
    }

// Layer 1 fused: msg-sum -> +selfloop +b1 -> relu -> @W2 -> *dinv -> t2s
__global__ __launch_bounds__(512)
void k_gather1(const int* __restrict__ packed, const int* __restrict__ cursor,
               const float* __restrict__ dinv, const float* __restrict__ h0s,
               const float* __restrict__ b1, const float* __restrict__ W2,
               float* __restrict__ t2s, int N) {
    __shared__ float acc[NPB * 17];
    __shared__ float sW2[256];
    int b = blockIdx.x, tid = threadIdx.x;
    for (int i = tid; i < NPB * 17; i += 512) acc[i] = 0.0f;
    if (tid < 256) sW2[tid] = W2[tid];
    __syncthreads();
    int s = b * CAP, n = cursor[b] - s;
    EDGE_ACC_LOOP(h0s)
    __syncthreads();
    int v0 = b * NPB, vcnt = min(NPB, N - v0);
    for (int i = tid; i < vcnt * 16; i += 512) {
        int vl = i >> 4, k = i & 15, v = v0 + vl;
        float dv = dinv[v];
        float val = dv * (acc[vl * 17 + k] + h0s[v * 16 + k]) + b1[k];
        acc[vl * 17 + k] = fmaxf(val, 0.0f);
    }
    __syncthreads();
    for (int i = tid; i < vcnt * 16; i += 512) {
        int vl = i >> 4, kp = i & 15, v = v0 + vl;
        const float* rr = acc + vl * 17;
        float a = 0.0f;
#pragma unroll
        for (int k = 0; k < 16; ++k) a += rr[k] * sW2[k * 16 + kp];
        t2s[v * 16 + kp] = dinv[v] * a;
    }
}

// Layer 2 fused: msg-sum -> +selfloop +b2 -> per-graph LDS pool -> global g
__global__ __launch_bounds__(512)
void k_gather2(const int* __restrict__ packed, const int* __restrict__ cursor,
               const float* __restrict__ dinv, const float* __restrict__ t2s,
               const float* __restrict__ b2, const int* __restrict__ batch,
               float* __restrict__ g, int N) {
    __shared__ float acc[NPB * 17];
    __shared__ float pacc[NPB * 16];
    int b = blockIdx.x, tid = threadIdx.x;
    for (int i = tid; i < NPB * 17; i += 512) acc[i] = 0.0f;
    for (int i = tid; i < NPB * 16; i += 512) pacc[i] = 0.0f;
    __syncthreads();
    int s = b * CAP, n = cursor[b] - s;
    EDGE_ACC_LOOP(t2s)
    __syncthreads();
    int v0 = b * NPB, vcnt = min(NPB, N - v0);
    int b0 = batch[v0];
    for (int i = tid; i < vcnt * 16; i += 512) {
        int vl = i >> 4, k = i & 15, v = v0 + vl;
        float dv = dinv[v];
        float val = dv * (acc[vl * 17 + k] + t2s[v * 16 + k]) + b2[k];
        int d = batch[v] - b0;                 // batch sorted
        if (d < NPB) atomicAdd(&pacc[d * 16 + k], val);
        else         atomicAdd(&g[batch[v] * 16 + k], val);
    }
    __syncthreads();
    int grange = min(batch[v0 + vcnt - 1] - b0 + 1, NPB);
    for (int i = tid; i < grange * 16; i += 512)
        atomicAdd(&g[(b0 + (i >> 4)) * 16 + (i & 15)], pacc[i]);
}

// logits = g @ Wl + bl (16x7), log_softmax over 7. One thread per graph.
__global__ void k_head(const float* __restrict__ g, const float* __restrict__ Wl,
                       const float* __restrict__ bl, float* __restrict__ out, int G) {
    int gi = blockIdx.x * blockDim.x + threadIdx.x;
    if (gi >= G) return;
    float gv[16];
#pragma unroll
    for (int kk = 0; kk < 16; ++kk) gv[kk] = g[gi * 16 + kk];
    float lo[7];
    float mx = -1e30f;
#pragma unroll
    for (int j = 0; j < 7; ++j) {
        float a = bl[j];
#pragma unroll
        for (int kk = 0; kk < 16; ++kk) a += gv[kk] * Wl[kk * 7 + j];
        lo[j] = a;
        mx = fmaxf(mx, a);
    }
    float ssum = 0.0f;
#pragma unroll
    for (int j = 0; j < 7; ++j) ssum += expf(lo[j] - mx);
    float lse = mx + logf(ssum);
#pragma unroll
    for (int j = 0; j < 7; ++j) out[gi * 7 + j] = lo[j] - lse;
}

extern "C" void kernel_launch(void* const* d_in, const int* in_sizes, int n_in,
                              void* d_out, int out_size, void* d_ws, size_t ws_size,
                              hipStream_t stream) {
    const float* x     = (const float*)d_in[0];
    const int*   ei    = (const int*)d_in[1];   // row = ei[0:E), col = ei[E:2E)
    const int*   batch = (const int*)d_in[3];
    const float* W1 = (const float*)d_in[4];
    const float* b1 = (const float*)d_in[5];
    const float* W2 = (const float*)d_in[6];
    const float* b2 = (const float*)d_in[7];
    const float* Wl = (const float*)d_in[8];
    const float* bl = (const float*)d_in[9];
    float* out = (float*)d_out;

    const int N = in_sizes[0] / 3;   // 100000 (< 2^17 required by packing)
    const int E = in_sizes[1] / 2;
    const int G = out_size / 7;
    const int NB = (N + NPB - 1) / NPB;   // 1000

    const int* row = ei;
    const int* col = ei + E;

    int*   cursor = (int*)d_ws;                   // NBMAX
    float* dinv   = (float*)(cursor + NBMAX);     // N
    int*   packed = (int*)(dinv + N);             // NB*CAP
    float* h0s    = (float*)(packed + NB * CAP);  // 16N
    float* t2s    = h0s + 16 * N;                 // 16N
    float* g      = t2s + 16 * N;                 // 16G

    const int TB = 256;
    int initN = max(NBMAX, G * 16);

    k_init<<<(initN + TB - 1) / TB, TB, 0, stream>>>(cursor, g, NB, G * 16);
    k_partition<<<(E + PT_TILE - 1) / PT_TILE, 512, 0, stream>>>(row, col, cursor, packed, E);
    k_deg_xw1<<<NB, 512, 0, stream>>>(packed, cursor, x, W1, dinv, h0s, N);
    k_gather1<<<NB, 512, 0, stream>>>(packed, cursor, dinv, h0s, b1, W2, t2s, N);
    k_gather2<<<NB, 512, 0, stream>>>(packed, cursor, dinv, t2s, b2, batch, g, N);
    k_head<<<(G + TB - 1) / TB, TB, 0, stream>>>(g, Wl, bl, out, G);
}

// Round 5
// 692.437 us; speedup vs baseline: 1.0476x; 1.0020x over previous
//
#include <hip/hip_runtime.h>
#include <math.h>

// GCN 2-layer + pool + head. Destination-bucketed, 4-edges-per-thread,
// LDS accumulators, dinv folded into features, bf16 feature tables
// (3.2 MB -> fits per-XCD L2, halves random-read bytes and latency).
//
// Bucket b = v / NPB (NPB=100, NB=1000). Edges partitioned into per-bucket
// segments of capacity CAP, packed = row | (c_local<<17).
//   h0s[v] = bf16( dinv[v]*(x[v]@W1) )
//   layer: acc[c] = sum_{(r->c)} h0s[r];  out = dinv[c]*(acc + h0s[c]) + bias
//
// Workspace: cursor[1024] int | dinv[N] f32 | packed[NB*CAP] int
//            | h0s[16N] bf16 | t2s[16N] bf16 | g[16G] f32   ~= 22.3 MB.

#define NPB     100
#define NBMAX   1024
#define CAP     3840    // mean E/NB = 3200, sigma ~57 -> 11 sigma; CAP%4==0
#define PT_TILE 8192

__device__ __forceinline__ float bf2f_lo(unsigned u) {
    union { unsigned i; float f; } c; c.i = u << 16; return c.f;
}
__device__ __forceinline__ float bf2f_hi(unsigned u) {
    union { unsigned i; float f; } c; c.i = u & 0xFFFF0000u; return c.f;
}
__device__ __forceinline__ unsigned short f2bf(float f) {   // round-nearest-even
    union { float f; unsigned i; } c; c.f = f;
    return (unsigned short)((c.i + 0x7FFFu + ((c.i >> 16) & 1u)) >> 16);
}

__global__ void k_init(int* cursor, float* g, int NB, int G16) {
    int i = blockIdx.x * blockDim.x + threadIdx.x;
    if (i < NB) cursor[i] = i * CAP;
    if (i < G16) g[i] = 0.0f;
}

__global__ __launch_bounds__(512)
void k_partition(const int* __restrict__ row, const int* __restrict__ col,
                 int* cursor, int* __restrict__ packed, int E) {
    __shared__ int hist[NBMAX];
    __shared__ int rstart[NBMAX];
    __shared__ int loff[NBMAX];
    int tid = threadIdx.x;
    for (int b = tid; b < NBMAX; b += 512) hist[b] = 0;
    __syncthreads();
    int e0 = blockIdx.x * PT_TILE;
#pragma unroll
    for (int j = 0; j < PT_TILE / 512; ++j) {
        int e = e0 + tid + j * 512;
        if (e < E) atomicAdd(&hist[col[e] / NPB], 1);
    }
    __syncthreads();
    for (int b = tid; b < NBMAX; b += 512) {
        loff[b] = 0;
        if (hist[b] > 0) rstart[b] = atomicAdd(&cursor[b], hist[b]);
    }
    __syncthreads();
#pragma unroll
    for (int j = 0; j < PT_TILE / 512; ++j) {
        int e = e0 + tid + j * 512;
        if (e < E) {
            int c = col[e];
            int b = c / NPB;
            int rank = atomicAdd(&loff[b], 1);
            packed[rstart[b] + rank] = row[e] | ((c - b * NPB) << 17);
        }
    }
}

// Per-bucket degree (LDS hist) -> dinv, then h0s = bf16(dinv * (x @ W1)).
__global__ __launch_bounds__(512)
void k_deg_xw1(const int* __restrict__ packed, const int* __restrict__ cursor,
               const float* __restrict__ x, const float* __restrict__ W1,
               float* __restrict__ dinv, unsigned short* __restrict__ h0s, int N) {
    __shared__ int   deg[NPB];
    __shared__ float sdinv[NPB];
    __shared__ float sW1[48];
    int b = blockIdx.x, tid = threadIdx.x;
    if (tid < NPB) deg[tid] = 0;
    if (tid < 48) sW1[tid] = W1[tid];
    __syncthreads();
    int s = b * CAP, n = cursor[b] - s;
    for (int i = tid; i < n; i += 512)
        atomicAdd(&deg[((unsigned)packed[s + i]) >> 17], 1);
    __syncthreads();
    int v0 = b * NPB;
    int vcnt = min(NPB, N - v0);
    if (tid < vcnt) {
        float dv = rsqrtf((float)(1 + deg[tid]));   // +1 self-loop
        sdinv[tid] = dv;
        dinv[v0 + tid] = dv;
    }
    __syncthreads();
    for (int i = tid; i < vcnt * 16; i += 512) {
        int vl = i >> 4, k = i & 15, v = v0 + vl;
        float x0 = x[v * 3 + 0], x1 = x[v * 3 + 1], x2 = x[v * 3 + 2];
        h0s[v * 16 + k] = f2bf(sdinv[vl] *
            (x0 * sW1[k] + x1 * sW1[16 + k] + x2 * sW1[32 + k]));
    }
}

// Edge accumulation: 4 edges per thread per sweep. One int4 packed load +
// 8 independent uint4 bf16-row loads in flight, then LDS atomics.
#define EDGE_ACC_LOOP(SRCB)                                                   \
    for (int base = tid * 4; base < n; base += 2048) {                        \
        int4 pk4 = *(const int4*)(packed + s + base);                         \
        unsigned pk[4] = {(unsigned)pk4.x, (unsigned)pk4.y,                   \
                          (unsigned)pk4.z, (unsigned)pk4.w};                  \
        bool ok[4]; int r[4], cl[4];                                          \
        _Pragma("unroll")                                                     \
        for (int j = 0; j < 4; ++j) {                                         \
            ok[j] = (base + j) < n;                                           \
            r[j]  = ok[j] ? (int)(pk[j] & 0x1FFFFu) : 0;                      \
            cl[j] = ok[j] ? (int)(pk[j] >> 17) : 0;                           \
        }                                                                     \
        uint4 lo[4], hi[4];                                                   \
        _Pragma("unroll")                                                     \
        for (int j = 0; j < 4; ++j) {                                         \
            const uint4* rp = (const uint4*)((SRCB) + r[j] * 16);             \
            lo[j] = rp[0]; hi[j] = rp[1];                                     \
        }                                                                     \
        _Pragma("unroll")                                                     \
        for (int j = 0; j < 4; ++j) {                                         \
            if (!ok[j]) continue;                                             \
            float* ar = acc + cl[j] * 17;                                     \
            atomicAdd(ar + 0,  bf2f_lo(lo[j].x));                             \
            atomicAdd(ar + 1,  bf2f_hi(lo[j].x));                             \
            atomicAdd(ar + 2,  bf2f_lo(lo[j].y));                             \
            atomicAdd(ar + 3,  bf2f_hi(lo[j].y));                             \
            atomicAdd(ar + 4,  bf2f_lo(lo[j].z));                             \
            atomicAdd(ar + 5,  bf2f_hi(lo[j].z));                             \
            atomicAdd(ar + 6,  bf2f_lo(lo[j].w));                             \
            atomicAdd(ar + 7,  bf2f_hi(lo[j].w));                             \
            atomicAdd(ar + 8,  bf2f_lo(hi[j].x));                             \
            atomicAdd(ar + 9,  bf2f_hi(hi[j].x));                             \
            atomicAdd(ar + 10, bf2f_lo(hi[j].y));                             \
            atomicAdd(ar + 11, bf2f_hi(hi[j].y));                             \
            atomicAdd(ar + 12, bf2f_lo(hi[j].z));                             \
            atomicAdd(ar + 13, bf2f_hi(hi[j].z));                             \
            atomicAdd(ar + 14, bf2f_lo(hi[j].w));                             \
            atomicAdd(ar + 15, bf2f_hi(hi[j].w));                             \
        }                                                                     \
    }

// Layer 1 fused: msg-sum -> +selfloop +b1 -> relu -> @W2 -> *dinv -> t2s (bf16)
__global__ __launch_bounds__(512)
void k_gather1(const int* __restrict__ packed, const int* __restrict__ cursor,
               const float* __restrict__ dinv, const unsigned short* __restrict__ h0s,
               const float* __restrict__ b1, const float* __restrict__ W2,
               unsigned short* __restrict__ t2s, int N) {
    __shared__ float acc[NPB * 17];
    __shared__ float sW2[256];
    int b = blockIdx.x, tid = threadIdx.x;
    for (int i = tid; i < NPB * 17; i += 512) acc[i] = 0.0f;
    if (tid < 256) sW2[tid] = W2[tid];
    __syncthreads();
    int s = b * CAP, n = cursor[b] - s;
    EDGE_ACC_LOOP(h0s)
    __syncthreads();
    int v0 = b * NPB, vcnt = min(NPB, N - v0);
    for (int i = tid; i < vcnt * 16; i += 512) {
        int vl = i >> 4, k = i & 15, v = v0 + vl;
        float dv = dinv[v];
        float self = bf2f_lo((unsigned)h0s[v * 16 + k]);
        float val = dv * (acc[vl * 17 + k] + self) + b1[k];
        acc[vl * 17 + k] = fmaxf(val, 0.0f);
    }
    __syncthreads();
    for (int i = tid; i < vcnt * 16; i += 512) {
        int vl = i >> 4, kp = i & 15, v = v0 + vl;
        const float* rr = acc + vl * 17;
        float a = 0.0f;
#pragma unroll
        for (int k = 0; k < 16; ++k) a += rr[k] * sW2[k * 16 + kp];
        t2s[v * 16 + kp] = f2bf(dinv[v] * a);
    }
}

// Layer 2 fused: msg-sum -> +selfloop +b2 -> per-graph LDS pool -> global g
__global__ __launch_bounds__(512)
void k_gather2(const int* __restrict__ packed, const int* __restrict__ cursor,
               const float* __restrict__ dinv, const unsigned short* __restrict__ t2s,
               const float* __restrict__ b2, const int* __restrict__ batch,
               float* __restrict__ g, int N) {
    __shared__ float acc[NPB * 17];
    __shared__ float pacc[NPB * 16];
    int b = blockIdx.x, tid = threadIdx.x;
    for (int i = tid; i < NPB * 17; i += 512) acc[i] = 0.0f;
    for (int i = tid; i < NPB * 16; i += 512) pacc[i] = 0.0f;
    __syncthreads();
    int s = b * CAP, n = cursor[b] - s;
    EDGE_ACC_LOOP(t2s)
    __syncthreads();
    int v0 = b * NPB, vcnt = min(NPB, N - v0);
    int b0 = batch[v0];
    for (int i = tid; i < vcnt * 16; i += 512) {
        int vl = i >> 4, k = i & 15, v = v0 + vl;
        float dv = dinv[v];
        float self = bf2f_lo((unsigned)t2s[v * 16 + k]);
        float val = dv * (acc[vl * 17 + k] + self) + b2[k];
        int d = batch[v] - b0;                 // batch sorted
        if (d < NPB) atomicAdd(&pacc[d * 16 + k], val);
        else         atomicAdd(&g[batch[v] * 16 + k], val);
    }
    __syncthreads();
    int grange = min(batch[v0 + vcnt - 1] - b0 + 1, NPB);
    for (int i = tid; i < grange * 16; i += 512)
        atomicAdd(&g[(b0 + (i >> 4)) * 16 + (i & 15)], pacc[i]);
}

// logits = g @ Wl + bl (16x7), log_softmax over 7. One thread per graph.
__global__ void k_head(const float* __restrict__ g, const float* __restrict__ Wl,
                       const float* __restrict__ bl, float* __restrict__ out, int G) {
    int gi = blockIdx.x * blockDim.x + threadIdx.x;
    if (gi >= G) return;
    float gv[16];
#pragma unroll
    for (int kk = 0; kk < 16; ++kk) gv[kk] = g[gi * 16 + kk];
    float lo[7];
    float mx = -1e30f;
#pragma unroll
    for (int j = 0; j < 7; ++j) {
        float a = bl[j];
#pragma unroll
        for (int kk = 0; kk < 16; ++kk) a += gv[kk] * Wl[kk * 7 + j];
        lo[j] = a;
        mx = fmaxf(mx, a);
    }
    float ssum = 0.0f;
#pragma unroll
    for (int j = 0; j < 7; ++j) ssum += expf(lo[j] - mx);
    float lse = mx + logf(ssum);
#pragma unroll
    for (int j = 0; j < 7; ++j) out[gi * 7 + j] = lo[j] - lse;
}

extern "C" void kernel_launch(void* const* d_in, const int* in_sizes, int n_in,
                              void* d_out, int out_size, void* d_ws, size_t ws_size,
                              hipStream_t stream) {
    const float* x     = (const float*)d_in[0];
    const int*   ei    = (const int*)d_in[1];   // row = ei[0:E), col = ei[E:2E)
    const int*   batch = (const int*)d_in[3];
    const float* W1 = (const float*)d_in[4];
    const float* b1 = (const float*)d_in[5];
    const float* W2 = (const float*)d_in[6];
    const float* b2 = (const float*)d_in[7];
    const float* Wl = (const float*)d_in[8];
    const float* bl = (const float*)d_in[9];
    float* out = (float*)d_out;

    const int N = in_sizes[0] / 3;   // 100000 (< 2^17 required by packing)
    const int E = in_sizes[1] / 2;
    const int G = out_size / 7;
    const int NB = (N + NPB - 1) / NPB;   // 1000

    const int* row = ei;
    const int* col = ei + E;

    int*            cursor = (int*)d_ws;                       // NBMAX
    float*          dinv   = (float*)(cursor + NBMAX);         // N
    int*            packed = (int*)(dinv + N);                 // NB*CAP
    unsigned short* h0s    = (unsigned short*)(packed + NB * CAP); // 16N bf16
    unsigned short* t2s    = h0s + 16 * N;                     // 16N bf16
    float*          g      = (float*)(t2s + 16 * N);           // 16G

    const int TB = 256;
    int initN = max(NBMAX, G * 16);

    k_init<<<(initN + TB - 1) / TB, TB, 0, stream>>>(cursor, g, NB, G * 16);
    k_partition<<<(E + PT_TILE - 1) / PT_TILE, 512, 0, stream>>>(row, col, cursor, packed, E);
    k_deg_xw1<<<NB, 512, 0, stream>>>(packed, cursor, x, W1, dinv, h0s, N);
    k_gather1<<<NB, 512, 0, stream>>>(packed, cursor, dinv, h0s, b1, W2, t2s, N);
    k_gather2<<<NB, 512, 0, stream>>>(packed, cursor, dinv, t2s, b2, batch, g, N);
    k_head<<<(G + TB - 1) / TB, TB, 0, stream>>>(g, Wl, bl, out, G);
}